// Round 3
// baseline (110.810 us; speedup 1.0000x reference)
//
#include <hip/hip_runtime.h>
#include <hip/hip_bf16.h>
#include <cstdint>
#include <cstddef>

// ---------------- problem constants ----------------
#define HW 36864            // 192*192
#define QT 128              // queries per block (M-tile)
#define NCHA 69             // partial channels: 64 fea + 3 sq + swc + sumw

constexpr bool is_valid_px(int v, int u) {
  int a = 2 * u - 63, b = 2 * v - 63;
  return a * a + b * b < 1024;   // integer-exact (==1024 impossible for odd,odd)
}
constexpr int count_valid() {
  int n = 0;
  for (int v = 0; v < 64; ++v)
    for (int u = 0; u < 64; ++u)
      if (is_valid_px(v, u)) ++n;
  return n;
}
constexpr int NV  = count_valid();          // 812
constexpr int NQT = (NV + QT - 1) / QT;     // 7 tiles of 128
constexpr int NQP = NQT * QT;               // 896 padded queries
constexpr int PLANE = 2 * NQP * NCHA;       // 123648 f32 per ks-plane

struct QTab {
  short idx[NQP];     // rank -> pixel (or -1 pad)
  short rank[4096];   // pixel -> rank (or -1 invalid)
};
constexpr QTab make_qtab() {
  QTab t{};
  int n = 0;
  for (int p = 0; p < 4096; ++p) {
    int v = p >> 6, u = p & 63;
    if (is_valid_px(v, u)) { t.idx[n] = (short)p; t.rank[p] = (short)n; ++n; }
    else t.rank[p] = -1;
  }
  for (int i = n; i < NQP; ++i) t.idx[i] = -1;
  return t;
}
__constant__ QTab g_qtab = make_qtab();

typedef short short8 __attribute__((ext_vector_type(8)));
typedef float f32x4  __attribute__((ext_vector_type(4)));

__device__ __forceinline__ ushort2 f2b2(float a, float b) {  // packed f32x2 -> bf16x2
  __hip_bfloat162 h = __float22bfloat162_rn(make_float2(a, b));
  return *(ushort2*)&h;
}
__device__ __forceinline__ short8 cvt8(float4 a, float4 b) {
  short8 o;
  ushort2 p0 = f2b2(a.x, a.y), p1 = f2b2(a.z, a.w);
  ushort2 p2 = f2b2(b.x, b.y), p3 = f2b2(b.z, b.w);
  o[0] = (short)p0.x; o[1] = (short)p0.y; o[2] = (short)p1.x; o[3] = (short)p1.y;
  o[4] = (short)p2.x; o[5] = (short)p2.y; o[6] = (short)p3.x; o[7] = (short)p3.y;
  return o;
}
__device__ __forceinline__ void pix2qn(int pix, float& x, float& y, float& z) {
  x = 0.f; y = 0.f; z = 0.f;
  if (pix >= 0) {
    int v = pix >> 6, u = pix & 63;
    float p = (float)(2 * u - 63) * (1.0f / 32.0f);
    float q = -(float)(2 * v - 63) * (1.0f / 32.0f);
    float d = 1.0f + p * p + q * q;
    x = 2.0f * p / d; y = 2.0f * q / d; z = (1.0f - p * p - q * q) / d;
  }
}

// ---------------- fused partial kernel (prep absorbed) ----------------
// DS-traffic-halved layout: 128 threads = 2 waves; wave wv owns queries
// [qt*128 + 64*wv, +64) as 4 MFMA strips of 16, FULL K.  Each B-fragment
// ds_read and each nv broadcast read now feeds 64 queries (was 32) ->
// total ds_read_b128 count halves vs the 4-wave/32q version.
// B rows per 64-px chunk: 0..63 fea, 64..66 fea^2(61..63), 67..69 nrm,
// 70 ones, 71..79 zero (rows 70..79 static: prefilled once, both buffers).
// Staging: thread t converts fea rows (t>>3)+16i, i=0..3 (8 px each);
// t<48 also handles dynamic rows 64..69; t<64 builds the nv table.
// partial layout: part[ ks*PLANE + (b*NQP+q)*NCHA + ch ]
template<int KSC>
__global__ __launch_bounds__(128, 2) void partial_kernel(
    const float* __restrict__ fea,
    const float* __restrict__ nrm,
    const float* __restrict__ msk,
    const float* __restrict__ lqn,
    float* __restrict__ part)
{
  constexpr int SLICE  = HW / KSC;
  constexpr int NCHUNK = SLICE / 64;

  __shared__ __align__(16) unsigned short v_s[2][80][72];  // 23040 B (pad: 2-way free)
  __shared__ __align__(16) float nrm4_s[2][64][4];         // permuted (Cc*n, bias)

  // XCD grouping: the 7 qt-blocks of a (b,ks) slice share blockIdx%8 and are
  // consecutive in r0 -> co-scheduled on one XCD -> fea slice served from L2.
  const int bx  = blockIdx.x;
  const int cls = bx & 7;
  const int r0  = bx >> 3;
  const int qt  = r0 % NQT;
  const int sh  = r0 / NQT;
  const int s   = sh * 8 + cls;       // slice id 0..2*KSC-1
  const int b   = s / KSC;
  const int ks  = s % KSC;

  const int t    = threadIdx.x;       // 0..127
  const int wv   = t >> 6;            // wave id: owns queries 64*wv..+63
  const int l    = t & 63;
  const int lq   = l >> 4;            // k-quad
  const int mrow = l & 15;

  const float Cc = __expf(lqn[0]) * 0.57735026919f;   // s/sqrt(3)

  // per-lane query geometry for this wave's four 16-row strips
  float qx[4], qy[4], qz[4];
  #pragma unroll
  for (int h = 0; h < 4; ++h)
    pix2qn(g_qtab.idx[qt * QT + 64 * wv + 16 * h + mrow], qx[h], qy[h], qz[h]);

  const int c0 = (t & 7) * 8;         // px offset within chunk
  const int rg = t >> 3;              // staging row 0..15 (fea rows rg+16i)
  // bank-permuted px index for nrm4 writes: px' = 32*(px>>5)+4*(px&7)+((px>>3)&3)
  const int pxp = 32 * (l >> 5) + 4 * (l & 7) + ((l >> 3) & 3);

  f32x4 acc[4][5];
  #pragma unroll
  for (int h = 0; h < 4; ++h)
    #pragma unroll
    for (int nt = 0; nt < 5; ++nt) acc[h][nt] = (f32x4)(0.0f);

  float4 pF[10];
  float nx, ny, nz, mk;
  const size_t feab = (size_t)b * 64 * HW;
  const size_t nrmb = (size_t)b * 3 * HW;
  const size_t mskb = (size_t)b * HW;
  const int ckb = ks * NCHUNK;

  // static rows 70 (ones) and 71..79 (zeros): fill once in both buffers
  if (t >= 48) {
    int idx = t - 48;                           // 0..79
    int row = 70 + (idx >> 3);                  // 70..79
    int col = (idx & 7) * 8;
    short cv = (row == 70) ? (short)0x3F80 : (short)0;   // bf16(1.0) / bf16(0)
    short8 o;
    #pragma unroll
    for (int i = 0; i < 8; ++i) o[i] = cv;
    *(short8*)&v_s[0][row][col] = o;
    *(short8*)&v_s[1][row][col] = o;
  }

  auto load_chunk = [&](int ck) {     // global -> registers (non-blocking)
    const size_t p0 = (size_t)((ckb + ck) * 64);
    if (t < 64) {                     // nv sources: 4 coalesced streams
      size_t px = p0 + (size_t)l;
      nx = nrm[nrmb + px];
      ny = nrm[nrmb + HW + px];
      nz = nrm[nrmb + 2 * HW + px];
      mk = msk[mskb + px];
    }
    const float* fb = fea + feab + p0 + c0;
    #pragma unroll
    for (int i = 0; i < 4; ++i) {
      pF[2 * i]     = *(const float4*)(fb + (size_t)(rg + 16 * i) * HW);
      pF[2 * i + 1] = *(const float4*)(fb + (size_t)(rg + 16 * i) * HW + 4);
    }
    if (t < 48) {                     // dynamic special rows 64..69
      const float* srcb = (t < 24)
          ? (fea + feab + (size_t)(61 + rg) * HW)       // rows 64..66: fea 61..63 (->^2)
          : (nrm + nrmb + (size_t)(rg - 3) * HW);       // rows 67..69: nrm 0..2
      pF[8] = *(const float4*)(srcb + p0 + c0);
      pF[9] = *(const float4*)(srcb + p0 + c0 + 4);
    }
  };
  auto store_chunk = [&](int buf) {   // registers -> LDS (cvt fused here)
    if (t < 64)
      *(float4*)&nrm4_s[buf][pxp][0] =
          make_float4(Cc * nx, Cc * ny, Cc * nz,
                      -Cc + (mk > 0.5f ? 0.f : -2000.f));
    #pragma unroll
    for (int i = 0; i < 4; ++i)
      *(short8*)&v_s[buf][rg + 16 * i][c0] = cvt8(pF[2 * i], pF[2 * i + 1]);
    if (t < 48) {
      float4 a = pF[8], bq = pF[9];
      if (t < 24) {                   // square rows 64..66
        a.x *= a.x; a.y *= a.y; a.z *= a.z; a.w *= a.w;
        bq.x *= bq.x; bq.y *= bq.y; bq.z *= bq.z; bq.w *= bq.w;
      }
      *(short8*)&v_s[buf][64 + rg][c0] = cvt8(a, bq);
    }
  };

  load_chunk(0);
  store_chunk(0);
  __syncthreads();

  for (int ck = 0; ck < NCHUNK; ++ck) {
    const int buf = ck & 1;
    if (ck + 1 < NCHUNK) load_chunk(ck + 1);   // overlap w/ compute below

    // ---- full K: 2 k-halves x {8 nv reads, 32 exps, 5 B reads, 20 MFMAs} ----
    #pragma unroll
    for (int kh = 0; kh < 2; ++kh) {
      float e0[8], e1[8], e2[8], e3[8];
      #pragma unroll
      for (int j = 0; j < 8; ++j) {
        // px = 32*kh + 8*lq + j -> permuted row 32*kh + 4*j + lq (conflict-free)
        const float4 nvv = *(const float4*)&nrm4_s[buf][32 * kh + 4 * j + lq][0];
        float t0 = fmaf(qx[0], nvv.x, fmaf(qy[0], nvv.y, fmaf(qz[0], nvv.z, nvv.w)));
        float t1 = fmaf(qx[1], nvv.x, fmaf(qy[1], nvv.y, fmaf(qz[1], nvv.z, nvv.w)));
        float t2 = fmaf(qx[2], nvv.x, fmaf(qy[2], nvv.y, fmaf(qz[2], nvv.z, nvv.w)));
        float t3 = fmaf(qx[3], nvv.x, fmaf(qy[3], nvv.y, fmaf(qz[3], nvv.z, nvv.w)));
        e0[j] = __expf(t0);
        e1[j] = __expf(t1);
        e2[j] = __expf(t2);
        e3[j] = __expf(t3);
      }
      short8 a0, a1, a2, a3;
      #pragma unroll
      for (int p = 0; p < 4; ++p) {
        ushort2 p0 = f2b2(e0[2 * p], e0[2 * p + 1]);
        ushort2 p1 = f2b2(e1[2 * p], e1[2 * p + 1]);
        ushort2 p2 = f2b2(e2[2 * p], e2[2 * p + 1]);
        ushort2 p3 = f2b2(e3[2 * p], e3[2 * p + 1]);
        a0[2 * p] = (short)p0.x; a0[2 * p + 1] = (short)p0.y;
        a1[2 * p] = (short)p1.x; a1[2 * p + 1] = (short)p1.y;
        a2[2 * p] = (short)p2.x; a2[2 * p + 1] = (short)p2.y;
        a3[2 * p] = (short)p3.x; a3[2 * p + 1] = (short)p3.y;
      }
      #pragma unroll
      for (int nt = 0; nt < 5; ++nt) {
        short8 bb = *(const short8*)&v_s[buf][16 * nt + mrow][32 * kh + 8 * lq];
        acc[0][nt] = __builtin_amdgcn_mfma_f32_16x16x32_bf16(a0, bb, acc[0][nt], 0, 0, 0);
        acc[1][nt] = __builtin_amdgcn_mfma_f32_16x16x32_bf16(a1, bb, acc[1][nt], 0, 0, 0);
        acc[2][nt] = __builtin_amdgcn_mfma_f32_16x16x32_bf16(a2, bb, acc[2][nt], 0, 0, 0);
        acc[3][nt] = __builtin_amdgcn_mfma_f32_16x16x32_bf16(a3, bb, acc[3][nt], 0, 0, 0);
      }
    }

    if (ck + 1 < NCHUNK) {
      store_chunk(buf ^ 1);
      __syncthreads();                 // single barrier per chunk
    }
  }

  // ---- epilogue: route extras via small LDS scratch aliased on v_s ----
  __syncthreads();                     // all v_s reads done before aliasing
  float* exs = (float*)&v_s[0][0][0];  // [128 q][9] f32 = 4608 B

  const size_t pbase = (size_t)ks * PLANE + ((size_t)b * NQP + (size_t)(qt * QT)) * NCHA;
  #pragma unroll
  for (int h = 0; h < 4; ++h) {
    #pragma unroll
    for (int nt = 0; nt < 4; ++nt)
      #pragma unroll
      for (int rr = 0; rr < 4; ++rr) {
        int qloc = 64 * wv + 16 * h + 4 * lq + rr;
        part[pbase + (size_t)qloc * NCHA + (size_t)(16 * nt + mrow)] = acc[h][nt][rr];
      }
    if (mrow < 7) {
      #pragma unroll
      for (int rr = 0; rr < 4; ++rr)
        exs[(64 * wv + 16 * h + 4 * lq + rr) * 9 + mrow] = acc[h][4][rr];
    }
  }
  __syncthreads();
  {
    float gx, gy, gz;
    pix2qn(g_qtab.idx[qt * QT + t], gx, gy, gz);   // t covers all 128 queries
    const float* E = exs + t * 9;
    float swc = gx * E[3] + gy * E[4] + gz * E[5];
    size_t o = pbase + (size_t)t * NCHA;
    part[o + 64] = E[0];
    part[o + 65] = E[1];
    part[o + 66] = E[2];
    part[o + 67] = swc;
    part[o + 68] = E[6];
  }
}

// single tail dispatch: blocks 0..447 reduce+normalize+scatter (4 queries each);
// blocks 448..895 zero-fill invalid-pixel output slots. No memsets needed.
#define NFIN 448                      // 2 * (NQP/4)
#define NTAIL (2 * NFIN)              // 896 total blocks

__global__ __launch_bounds__(256) void finalize_kernel(
    const float* __restrict__ part,
    float* __restrict__ out,
    int ksc)
{
  const int blk = blockIdx.x;
  const int t   = threadIdx.x;

  if (blk < NFIN) {
    __shared__ float sm[4][NCHA];     // 1.1 KB
    const int b   = blk / (NFIN / 2);
    const int rem = blk % (NFIN / 2);
    const int q0  = rem * 4;          // queries q0..q0+3

    const size_t colbase = ((size_t)b * NQP + (size_t)q0) * NCHA;
    for (int i = t; i < 4 * NCHA; i += 256) {      // 276 sums, coalesced bursts
      float sv = 0.f;
      const size_t off = colbase + (size_t)i;
      #pragma unroll 8
      for (int k = 0; k < ksc; ++k) sv += part[(size_t)k * PLANE + off];
      sm[0][i] = sv;
    }
    __syncthreads();

    for (int i = t; i < 4 * NCHA; i += 256) {
      const int ql = i / NCHA;        // 0..3
      const int oc = i % NCHA;        // output channel
      const int pix = g_qtab.idx[q0 + ql];
      if (pix < 0) continue;
      const float* A = sm[ql];
      const float inv = 1.0f / (A[68] + 1e-9f);
      float gx, gy, gz;
      pix2qn(pix, gx, gy, gz);
      float val;
      if (oc == 0)      val = A[67] * inv;               // rm_cos
      else if (oc == 1) {                                // var
        val = 0.f;
        #pragma unroll
        for (int j = 0; j < 3; ++j) {
          float m  = A[61 + j] * inv;
          float sq = A[64 + j] * inv;
          val += sq - m * m;
        }
      }
      else if (oc == 2) val = gx;
      else if (oc == 3) val = gy;
      else if (oc == 4) val = gz;
      else              val = A[oc - 5] * inv;           // mapped features
      out[((size_t)b * NCHA + (size_t)oc) * 4096 + pix] = val;
    }
  } else {
    // zero-fill: all invalid-pixel slots across both batches (disjoint writes)
    const int start = (blk - NFIN) * 256 + t;
    const int strd  = (NTAIL - NFIN) * 256;
    const int TOT   = 2 * NCHA * 4096;
    for (int i = start; i < TOT; i += strd) {
      if (g_qtab.rank[i & 4095] < 0) out[i] = 0.0f;
    }
  }
}

extern "C" void kernel_launch(void* const* d_in, const int* in_sizes, int n_in,
                              void* d_out, int out_size, void* d_ws, size_t ws_size,
                              hipStream_t stream) {
  const float* fea = (const float*)d_in[0];
  const float* nrm = (const float*)d_in[1];
  const float* msk = (const float*)d_in[2];
  const float* lqn = (const float*)d_in[3];
  float* part = (float*)d_ws;
  float* out  = (float*)d_out;

  const size_t need64 = (size_t)64 * PLANE * sizeof(float);   // 31.7 MB
  const size_t need32 = (size_t)32 * PLANE * sizeof(float);   // 15.8 MB
  if (ws_size >= need64) {            // 896 blocks x 2 waves -> single residency round
    partial_kernel<64><<<dim3(2 * 64 * NQT), 128, 0, stream>>>(fea, nrm, msk, lqn, part);
    finalize_kernel<<<dim3(NTAIL), 256, 0, stream>>>(part, out, 64);
  } else if (ws_size >= need32) {
    partial_kernel<32><<<dim3(2 * 32 * NQT), 128, 0, stream>>>(fea, nrm, msk, lqn, part);
    finalize_kernel<<<dim3(NTAIL), 256, 0, stream>>>(part, out, 32);
  } else {
    partial_kernel<16><<<dim3(2 * 16 * NQT), 128, 0, stream>>>(fea, nrm, msk, lqn, part);
    finalize_kernel<<<dim3(NTAIL), 256, 0, stream>>>(part, out, 16);
  }
}

// Round 4
// 100.773 us; speedup vs baseline: 1.0996x; 1.0996x over previous
//
#include <hip/hip_runtime.h>
#include <hip/hip_bf16.h>
#include <hip/hip_fp16.h>
#include <cstdint>
#include <cstddef>

// ---------------- problem constants ----------------
#define HW 36864            // 192*192
#define QT 128              // queries per block (M-tile)
#define NCHA 69             // partial channels: 64 fea + 3 sq + swc + sumw

constexpr bool is_valid_px(int v, int u) {
  int a = 2 * u - 63, b = 2 * v - 63;
  return a * a + b * b < 1024;   // integer-exact (==1024 impossible for odd,odd)
}
constexpr int count_valid() {
  int n = 0;
  for (int v = 0; v < 64; ++v)
    for (int u = 0; u < 64; ++u)
      if (is_valid_px(v, u)) ++n;
  return n;
}
constexpr int NV  = count_valid();          // 812
constexpr int NQT = (NV + QT - 1) / QT;     // 7 tiles of 128
constexpr int NQP = NQT * QT;               // 896 padded queries
constexpr int PLANE = 2 * NQP * NCHA;       // 123648 fp16 per ks-plane (even)

struct QTab {
  short idx[NQP];     // rank -> pixel (or -1 pad)
  short rank[4096];   // pixel -> rank (or -1 invalid)
};
constexpr QTab make_qtab() {
  QTab t{};
  int n = 0;
  for (int p = 0; p < 4096; ++p) {
    int v = p >> 6, u = p & 63;
    if (is_valid_px(v, u)) { t.idx[n] = (short)p; t.rank[p] = (short)n; ++n; }
    else t.rank[p] = -1;
  }
  for (int i = n; i < NQP; ++i) t.idx[i] = -1;
  return t;
}
__constant__ QTab g_qtab = make_qtab();

typedef short short8 __attribute__((ext_vector_type(8)));
typedef float f32x4  __attribute__((ext_vector_type(4)));

__device__ __forceinline__ ushort2 f2b2(float a, float b) {  // packed f32x2 -> bf16x2
  __hip_bfloat162 h = __float22bfloat162_rn(make_float2(a, b));
  return *(ushort2*)&h;
}
__device__ __forceinline__ short8 cvt8(float4 a, float4 b) {
  short8 o;
  ushort2 p0 = f2b2(a.x, a.y), p1 = f2b2(a.z, a.w);
  ushort2 p2 = f2b2(b.x, b.y), p3 = f2b2(b.z, b.w);
  o[0] = (short)p0.x; o[1] = (short)p0.y; o[2] = (short)p1.x; o[3] = (short)p1.y;
  o[4] = (short)p2.x; o[5] = (short)p2.y; o[6] = (short)p3.x; o[7] = (short)p3.y;
  return o;
}
__device__ __forceinline__ void pix2qn(int pix, float& x, float& y, float& z) {
  x = 0.f; y = 0.f; z = 0.f;
  if (pix >= 0) {
    int v = pix >> 6, u = pix & 63;
    float p = (float)(2 * u - 63) * (1.0f / 32.0f);
    float q = -(float)(2 * v - 63) * (1.0f / 32.0f);
    float d = 1.0f + p * p + q * q;
    x = 2.0f * p / d; y = 2.0f * q / d; z = (1.0f - p * p - q * q) / d;
  }
}

// ---------------- fused partial kernel (round-2 structure, fp16 partials) ----------------
// 256 threads = 4 waves; wave w owns queries [qt*128 + 32w, +32), FULL K.
// B rows per 64-px chunk: 0..63 fea, 64..66 fea^2(61..63), 67..69 nrm,
// 70 ones, 71..79 zero (rows 70..79 static: prefilled once, both buffers).
// Partials stored as fp16 (range-checked: |partial| <= ~17k << 65504; w==0
// exact for masked px; per-slice sumw >> fp16 denormal floor) -> halves the
// part-buffer HBM round trip (31.7 MB -> 15.8 MB each way).
// partial layout: part[ ks*PLANE + (b*NQP+q)*NCHA + ch ]
template<int KSC>
__global__ __launch_bounds__(256, 4) void partial_kernel(
    const float* __restrict__ fea,
    const float* __restrict__ nrm,
    const float* __restrict__ msk,
    const float* __restrict__ lqn,
    __half* __restrict__ part)
{
  constexpr int SLICE  = HW / KSC;
  constexpr int NCHUNK = SLICE / 64;

  __shared__ __align__(16) unsigned short v_s[2][80][72];  // 23040 B (pad: 2-way free)
  __shared__ __align__(16) float nrm4_s[2][64][4];         // permuted (Cc*n, bias)

  // XCD grouping: the 7 qt-blocks of a (b,ks) slice share blockIdx%8 and are
  // consecutive in r0 -> co-scheduled on one XCD -> fea slice served from L2.
  const int bx  = blockIdx.x;
  const int cls = bx & 7;
  const int r0  = bx >> 3;
  const int qt  = r0 % NQT;
  const int sh  = r0 / NQT;
  const int s   = sh * 8 + cls;       // slice id 0..2*KSC-1
  const int b   = s / KSC;
  const int ks  = s % KSC;

  const int t    = threadIdx.x;       // 0..255
  const int wv   = t >> 6;            // wave id: owns queries 32*wv..+31
  const int l    = t & 63;
  const int lq   = l >> 4;            // k-quad
  const int mrow = l & 15;

  const float Cc = __expf(lqn[0]) * 0.57735026919f;   // s/sqrt(3)

  // per-lane query geometry for this wave's two 16-row strips
  float qx[2], qy[2], qz[2];
  pix2qn(g_qtab.idx[qt * QT + 32 * wv + mrow],      qx[0], qy[0], qz[0]);
  pix2qn(g_qtab.idx[qt * QT + 32 * wv + 16 + mrow], qx[1], qy[1], qz[1]);

  const int c0 = (t & 7) * 8;         // px offset within chunk
  const int rg = t >> 3;              // staging row 0..31
  // bank-permuted px index for nrm4 writes: px' = 32*(px>>5)+4*(px&7)+((px>>3)&3)
  const int pxp = 32 * (l >> 5) + 4 * (l & 7) + ((l >> 3) & 3);

  f32x4 acc[2][5];
  #pragma unroll
  for (int h = 0; h < 2; ++h)
    #pragma unroll
    for (int nt = 0; nt < 5; ++nt) acc[h][nt] = (f32x4)(0.0f);

  float4 pF[6];
  float nx, ny, nz, mk;
  const size_t feab = (size_t)b * 64 * HW;
  const size_t nrmb = (size_t)b * 3 * HW;
  const size_t mskb = (size_t)b * HW;
  const int ckb = ks * NCHUNK;

  // static rows 70 (ones) and 71..79 (zeros): fill once in both buffers
  if (t >= 48 && t < 128) {
    int row = 64 + rg;                          // 70..79
    short cv = (row == 70) ? (short)0x3F80 : (short)0;   // bf16(1.0) / bf16(0)
    short8 o;
    #pragma unroll
    for (int i = 0; i < 8; ++i) o[i] = cv;
    *(short8*)&v_s[0][row][c0] = o;
    *(short8*)&v_s[1][row][c0] = o;
  }

  auto load_chunk = [&](int ck) {     // global -> registers (non-blocking)
    const size_t p0 = (size_t)((ckb + ck) * 64);
    if (t < 64) {                     // nv sources: 4 coalesced streams
      size_t px = p0 + (size_t)l;
      nx = nrm[nrmb + px];
      ny = nrm[nrmb + HW + px];
      nz = nrm[nrmb + 2 * HW + px];
      mk = msk[mskb + px];
    }
    const float* fb = fea + feab + p0 + c0;
    pF[0] = *(const float4*)(fb + (size_t)rg * HW);
    pF[1] = *(const float4*)(fb + (size_t)rg * HW + 4);
    pF[2] = *(const float4*)(fb + (size_t)(rg + 32) * HW);
    pF[3] = *(const float4*)(fb + (size_t)(rg + 32) * HW + 4);
    if (t < 48) {                     // dynamic special rows 64..69
      const float* srcb = (t < 24)
          ? (fea + feab + (size_t)(61 + rg) * HW)       // rows 64..66: fea 61..63 (->^2)
          : (nrm + nrmb + (size_t)(rg - 3) * HW);       // rows 67..69: nrm 0..2
      pF[4] = *(const float4*)(srcb + p0 + c0);
      pF[5] = *(const float4*)(srcb + p0 + c0 + 4);
    }
  };
  auto store_chunk = [&](int buf) {   // registers -> LDS (cvt fused here)
    if (t < 64)
      *(float4*)&nrm4_s[buf][pxp][0] =
          make_float4(Cc * nx, Cc * ny, Cc * nz,
                      -Cc + (mk > 0.5f ? 0.f : -2000.f));
    *(short8*)&v_s[buf][rg][c0]      = cvt8(pF[0], pF[1]);
    *(short8*)&v_s[buf][rg + 32][c0] = cvt8(pF[2], pF[3]);
    if (t < 48) {
      float4 a = pF[4], bq = pF[5];
      if (t < 24) {                   // square rows 64..66
        a.x *= a.x; a.y *= a.y; a.z *= a.z; a.w *= a.w;
        bq.x *= bq.x; bq.y *= bq.y; bq.z *= bq.z; bq.w *= bq.w;
      }
      *(short8*)&v_s[buf][64 + rg][c0] = cvt8(a, bq);
    }
  };

  load_chunk(0);
  store_chunk(0);
  __syncthreads();

  for (int ck = 0; ck < NCHUNK; ++ck) {
    const int buf = ck & 1;
    if (ck + 1 < NCHUNK) load_chunk(ck + 1);   // overlap w/ compute below

    // ---- full K: 2 k-halves x {8 nv reads, 16 exps, 5 B reads, 10 MFMAs} ----
    #pragma unroll
    for (int kh = 0; kh < 2; ++kh) {
      float e0[8], e1[8];
      #pragma unroll
      for (int j = 0; j < 8; ++j) {
        // px = 32*kh + 8*lq + j -> permuted row 32*kh + 4*j + lq (conflict-free)
        const float4 nvv = *(const float4*)&nrm4_s[buf][32 * kh + 4 * j + lq][0];
        float t0 = fmaf(qx[0], nvv.x, fmaf(qy[0], nvv.y, fmaf(qz[0], nvv.z, nvv.w)));
        float t1 = fmaf(qx[1], nvv.x, fmaf(qy[1], nvv.y, fmaf(qz[1], nvv.z, nvv.w)));
        e0[j] = __expf(t0);
        e1[j] = __expf(t1);
      }
      short8 a0, a1;
      #pragma unroll
      for (int p = 0; p < 4; ++p) {
        ushort2 p0 = f2b2(e0[2 * p], e0[2 * p + 1]);
        ushort2 p1 = f2b2(e1[2 * p], e1[2 * p + 1]);
        a0[2 * p] = (short)p0.x; a0[2 * p + 1] = (short)p0.y;
        a1[2 * p] = (short)p1.x; a1[2 * p + 1] = (short)p1.y;
      }
      #pragma unroll
      for (int nt = 0; nt < 5; ++nt) {
        short8 bb = *(const short8*)&v_s[buf][16 * nt + mrow][32 * kh + 8 * lq];
        acc[0][nt] = __builtin_amdgcn_mfma_f32_16x16x32_bf16(a0, bb, acc[0][nt], 0, 0, 0);
        acc[1][nt] = __builtin_amdgcn_mfma_f32_16x16x32_bf16(a1, bb, acc[1][nt], 0, 0, 0);
      }
    }

    if (ck + 1 < NCHUNK) {
      store_chunk(buf ^ 1);
      __syncthreads();                 // single barrier per chunk
    }
  }

  // ---- epilogue: no K-merge needed; route extras via small LDS scratch ----
  __syncthreads();                     // all v_s reads done before aliasing
  float* exs = (float*)&v_s[0][0][0];  // [128 q][9] f32 = 4608 B

  const size_t pbase = (size_t)ks * PLANE + ((size_t)b * NQP + (size_t)(qt * QT)) * NCHA;
  #pragma unroll
  for (int h = 0; h < 2; ++h) {
    #pragma unroll
    for (int nt = 0; nt < 4; ++nt)
      #pragma unroll
      for (int rr = 0; rr < 4; ++rr) {
        int qloc = 32 * wv + 16 * h + 4 * lq + rr;
        part[pbase + (size_t)qloc * NCHA + (size_t)(16 * nt + mrow)] =
            __float2half(acc[h][nt][rr]);
      }
    if (mrow < 7) {
      #pragma unroll
      for (int rr = 0; rr < 4; ++rr)
        exs[(32 * wv + 16 * h + 4 * lq + rr) * 9 + mrow] = acc[h][4][rr];
    }
  }
  __syncthreads();
  if (t < QT) {
    float gx, gy, gz;
    pix2qn(g_qtab.idx[qt * QT + t], gx, gy, gz);
    const float* E = exs + t * 9;
    float swc = gx * E[3] + gy * E[4] + gz * E[5];
    size_t o = pbase + (size_t)t * NCHA;
    part[o + 64] = __float2half(E[0]);
    part[o + 65] = __float2half(E[1]);
    part[o + 66] = __float2half(E[2]);
    part[o + 67] = __float2half(swc);
    part[o + 68] = __float2half(E[6]);
  }
}

// single tail dispatch: blocks 0..447 reduce+normalize+scatter (4 queries each,
// half2-vectorized k-reduction: 138 pairs over 256 threads, worst thread 64 loads);
// blocks 448..895 zero-fill invalid-pixel output slots. No memsets needed.
#define NFIN 448                      // 2 * (NQP/4)
#define NTAIL (2 * NFIN)              // 896 total blocks

__global__ __launch_bounds__(256) void finalize_kernel(
    const __half* __restrict__ part,
    float* __restrict__ out,
    int ksc)
{
  const int blk = blockIdx.x;
  const int t   = threadIdx.x;

  if (blk < NFIN) {
    __shared__ float sm[4][NCHA];     // 1.1 KB
    const int b   = blk / (NFIN / 2);
    const int rem = blk % (NFIN / 2);
    const int q0  = rem * 4;          // queries q0..q0+3

    // colbase is even (q0 % 4 == 0, NQP*NCHA even) -> half2-aligned
    const size_t colbase2 = (((size_t)b * NQP + (size_t)q0) * NCHA) >> 1;
    const __half2* p2 = (const __half2*)part;
    for (int i2 = t; i2 < 2 * NCHA; i2 += 256) {   // 138 half2 pairs
      float sx = 0.f, sy = 0.f;
      const size_t off = colbase2 + (size_t)i2;
      #pragma unroll 8
      for (int k = 0; k < ksc; ++k) {
        float2 fv = __half22float2(p2[(size_t)k * (PLANE / 2) + off]);
        sx += fv.x; sy += fv.y;
      }
      sm[0][2 * i2]     = sx;
      sm[0][2 * i2 + 1] = sy;
    }
    __syncthreads();

    for (int i = t; i < 4 * NCHA; i += 256) {
      const int ql = i / NCHA;        // 0..3
      const int oc = i % NCHA;        // output channel
      const int pix = g_qtab.idx[q0 + ql];
      if (pix < 0) continue;
      const float* A = sm[ql];
      const float inv = 1.0f / (A[68] + 1e-9f);
      float gx, gy, gz;
      pix2qn(pix, gx, gy, gz);
      float val;
      if (oc == 0)      val = A[67] * inv;               // rm_cos
      else if (oc == 1) {                                // var
        val = 0.f;
        #pragma unroll
        for (int j = 0; j < 3; ++j) {
          float m  = A[61 + j] * inv;
          float sq = A[64 + j] * inv;
          val += sq - m * m;
        }
      }
      else if (oc == 2) val = gx;
      else if (oc == 3) val = gy;
      else if (oc == 4) val = gz;
      else              val = A[oc - 5] * inv;           // mapped features
      out[((size_t)b * NCHA + (size_t)oc) * 4096 + pix] = val;
    }
  } else {
    // zero-fill: all invalid-pixel slots across both batches (disjoint writes)
    const int start = (blk - NFIN) * 256 + t;
    const int strd  = (NTAIL - NFIN) * 256;
    const int TOT   = 2 * NCHA * 4096;
    for (int i = start; i < TOT; i += strd) {
      if (g_qtab.rank[i & 4095] < 0) out[i] = 0.0f;
    }
  }
}

extern "C" void kernel_launch(void* const* d_in, const int* in_sizes, int n_in,
                              void* d_out, int out_size, void* d_ws, size_t ws_size,
                              hipStream_t stream) {
  const float* fea = (const float*)d_in[0];
  const float* nrm = (const float*)d_in[1];
  const float* msk = (const float*)d_in[2];
  const float* lqn = (const float*)d_in[3];
  __half* part = (__half*)d_ws;
  float* out  = (float*)d_out;

  const size_t need64 = (size_t)64 * PLANE * sizeof(__half);   // 15.8 MB
  const size_t need32 = (size_t)32 * PLANE * sizeof(__half);   // 7.9 MB
  if (ws_size >= need64) {            // 896 blocks x 4 waves -> ~2 rounds residency
    partial_kernel<64><<<dim3(2 * 64 * NQT), 256, 0, stream>>>(fea, nrm, msk, lqn, part);
    finalize_kernel<<<dim3(NTAIL), 256, 0, stream>>>(part, out, 64);
  } else if (ws_size >= need32) {
    partial_kernel<32><<<dim3(2 * 32 * NQT), 256, 0, stream>>>(fea, nrm, msk, lqn, part);
    finalize_kernel<<<dim3(NTAIL), 256, 0, stream>>>(part, out, 32);
  } else {
    partial_kernel<16><<<dim3(2 * 16 * NQT), 256, 0, stream>>>(fea, nrm, msk, lqn, part);
    finalize_kernel<<<dim3(NTAIL), 256, 0, stream>>>(part, out, 16);
  }
}

// Round 5
// 99.513 us; speedup vs baseline: 1.1135x; 1.0127x over previous
//
#include <hip/hip_runtime.h>
#include <hip/hip_bf16.h>
#include <hip/hip_fp16.h>
#include <cstdint>
#include <cstddef>

// ---------------- problem constants ----------------
#define HW 36864            // 192*192
#define QT 128              // queries per block (M-tile)
#define NCHA 69             // real partial channels: 64 fea + 3 sq + swc + sumw
#define NCHA_P 72           // padded part stride (72 = 9 x half8 -> 16B units)

constexpr bool is_valid_px(int v, int u) {
  int a = 2 * u - 63, b = 2 * v - 63;
  return a * a + b * b < 1024;   // integer-exact (==1024 impossible for odd,odd)
}
constexpr int count_valid() {
  int n = 0;
  for (int v = 0; v < 64; ++v)
    for (int u = 0; u < 64; ++u)
      if (is_valid_px(v, u)) ++n;
  return n;
}
constexpr int NV  = count_valid();          // 812
constexpr int NQT = (NV + QT - 1) / QT;     // 7 tiles of 128
constexpr int NQP = NQT * QT;               // 896 padded queries
constexpr int PLANE = 2 * NQP * NCHA_P;     // 129024 fp16 per ks-plane (/8 = 16128)

struct QTab {
  short idx[NQP];     // rank -> pixel (or -1 pad)
  short rank[4096];   // pixel -> rank (or -1 invalid)
};
constexpr QTab make_qtab() {
  QTab t{};
  int n = 0;
  for (int p = 0; p < 4096; ++p) {
    int v = p >> 6, u = p & 63;
    if (is_valid_px(v, u)) { t.idx[n] = (short)p; t.rank[p] = (short)n; ++n; }
    else t.rank[p] = -1;
  }
  for (int i = n; i < NQP; ++i) t.idx[i] = -1;
  return t;
}
__constant__ QTab g_qtab = make_qtab();

typedef short short8 __attribute__((ext_vector_type(8)));
typedef float f32x4  __attribute__((ext_vector_type(4)));

__device__ __forceinline__ ushort2 f2b2(float a, float b) {  // packed f32x2 -> bf16x2
  __hip_bfloat162 h = __float22bfloat162_rn(make_float2(a, b));
  return *(ushort2*)&h;
}
__device__ __forceinline__ short8 cvt8(float4 a, float4 b) {
  short8 o;
  ushort2 p0 = f2b2(a.x, a.y), p1 = f2b2(a.z, a.w);
  ushort2 p2 = f2b2(b.x, b.y), p3 = f2b2(b.z, b.w);
  o[0] = (short)p0.x; o[1] = (short)p0.y; o[2] = (short)p1.x; o[3] = (short)p1.y;
  o[4] = (short)p2.x; o[5] = (short)p2.y; o[6] = (short)p3.x; o[7] = (short)p3.y;
  return o;
}
__device__ __forceinline__ void pix2qn(int pix, float& x, float& y, float& z) {
  x = 0.f; y = 0.f; z = 0.f;
  if (pix >= 0) {
    int v = pix >> 6, u = pix & 63;
    float p = (float)(2 * u - 63) * (1.0f / 32.0f);
    float q = -(float)(2 * v - 63) * (1.0f / 32.0f);
    float d = 1.0f + p * p + q * q;
    x = 2.0f * p / d; y = 2.0f * q / d; z = (1.0f - p * p - q * q) / d;
  }
}

// ---------------- fused partial kernel (round-4 structure, stride 72) ----------------
// 256 threads = 4 waves; wave w owns queries [qt*128 + 32w, +32), FULL K.
// B rows per 64-px chunk: 0..63 fea, 64..66 fea^2(61..63), 67..69 nrm,
// 70 ones, 71..79 zero (rows 70..79 static: prefilled once, both buffers).
// Partials stored fp16 at stride NCHA_P=72 (ch 69..71 zeroed pad).
// partial layout: part[ ks*PLANE + (b*NQP+q)*NCHA_P + ch ]
template<int KSC>
__global__ __launch_bounds__(256, 4) void partial_kernel(
    const float* __restrict__ fea,
    const float* __restrict__ nrm,
    const float* __restrict__ msk,
    const float* __restrict__ lqn,
    __half* __restrict__ part)
{
  constexpr int SLICE  = HW / KSC;
  constexpr int NCHUNK = SLICE / 64;

  __shared__ __align__(16) unsigned short v_s[2][80][72];  // 23040 B (pad: 2-way free)
  __shared__ __align__(16) float nrm4_s[2][64][4];         // permuted (Cc*n, bias)

  // XCD grouping: the 7 qt-blocks of a (b,ks) slice share blockIdx%8 and are
  // consecutive in r0 -> co-scheduled on one XCD -> fea slice served from L2.
  const int bx  = blockIdx.x;
  const int cls = bx & 7;
  const int r0  = bx >> 3;
  const int qt  = r0 % NQT;
  const int sh  = r0 / NQT;
  const int s   = sh * 8 + cls;       // slice id 0..2*KSC-1
  const int b   = s / KSC;
  const int ks  = s % KSC;

  const int t    = threadIdx.x;       // 0..255
  const int wv   = t >> 6;            // wave id: owns queries 32*wv..+31
  const int l    = t & 63;
  const int lq   = l >> 4;            // k-quad
  const int mrow = l & 15;

  const float Cc = __expf(lqn[0]) * 0.57735026919f;   // s/sqrt(3)

  // per-lane query geometry for this wave's two 16-row strips
  float qx[2], qy[2], qz[2];
  pix2qn(g_qtab.idx[qt * QT + 32 * wv + mrow],      qx[0], qy[0], qz[0]);
  pix2qn(g_qtab.idx[qt * QT + 32 * wv + 16 + mrow], qx[1], qy[1], qz[1]);

  const int c0 = (t & 7) * 8;         // px offset within chunk
  const int rg = t >> 3;              // staging row 0..31
  // bank-permuted px index for nrm4 writes: px' = 32*(px>>5)+4*(px&7)+((px>>3)&3)
  const int pxp = 32 * (l >> 5) + 4 * (l & 7) + ((l >> 3) & 3);

  f32x4 acc[2][5];
  #pragma unroll
  for (int h = 0; h < 2; ++h)
    #pragma unroll
    for (int nt = 0; nt < 5; ++nt) acc[h][nt] = (f32x4)(0.0f);

  float4 pF[6];
  float nx, ny, nz, mk;
  const size_t feab = (size_t)b * 64 * HW;
  const size_t nrmb = (size_t)b * 3 * HW;
  const size_t mskb = (size_t)b * HW;
  const int ckb = ks * NCHUNK;

  // static rows 70 (ones) and 71..79 (zeros): fill once in both buffers
  if (t >= 48 && t < 128) {
    int row = 64 + rg;                          // 70..79
    short cv = (row == 70) ? (short)0x3F80 : (short)0;   // bf16(1.0) / bf16(0)
    short8 o;
    #pragma unroll
    for (int i = 0; i < 8; ++i) o[i] = cv;
    *(short8*)&v_s[0][row][c0] = o;
    *(short8*)&v_s[1][row][c0] = o;
  }

  auto load_chunk = [&](int ck) {     // global -> registers (non-blocking)
    const size_t p0 = (size_t)((ckb + ck) * 64);
    if (t < 64) {                     // nv sources: 4 coalesced streams
      size_t px = p0 + (size_t)l;
      nx = nrm[nrmb + px];
      ny = nrm[nrmb + HW + px];
      nz = nrm[nrmb + 2 * HW + px];
      mk = msk[mskb + px];
    }
    const float* fb = fea + feab + p0 + c0;
    pF[0] = *(const float4*)(fb + (size_t)rg * HW);
    pF[1] = *(const float4*)(fb + (size_t)rg * HW + 4);
    pF[2] = *(const float4*)(fb + (size_t)(rg + 32) * HW);
    pF[3] = *(const float4*)(fb + (size_t)(rg + 32) * HW + 4);
    if (t < 48) {                     // dynamic special rows 64..69
      const float* srcb = (t < 24)
          ? (fea + feab + (size_t)(61 + rg) * HW)       // rows 64..66: fea 61..63 (->^2)
          : (nrm + nrmb + (size_t)(rg - 3) * HW);       // rows 67..69: nrm 0..2
      pF[4] = *(const float4*)(srcb + p0 + c0);
      pF[5] = *(const float4*)(srcb + p0 + c0 + 4);
    }
  };
  auto store_chunk = [&](int buf) {   // registers -> LDS (cvt fused here)
    if (t < 64)
      *(float4*)&nrm4_s[buf][pxp][0] =
          make_float4(Cc * nx, Cc * ny, Cc * nz,
                      -Cc + (mk > 0.5f ? 0.f : -2000.f));
    *(short8*)&v_s[buf][rg][c0]      = cvt8(pF[0], pF[1]);
    *(short8*)&v_s[buf][rg + 32][c0] = cvt8(pF[2], pF[3]);
    if (t < 48) {
      float4 a = pF[4], bq = pF[5];
      if (t < 24) {                   // square rows 64..66
        a.x *= a.x; a.y *= a.y; a.z *= a.z; a.w *= a.w;
        bq.x *= bq.x; bq.y *= bq.y; bq.z *= bq.z; bq.w *= bq.w;
      }
      *(short8*)&v_s[buf][64 + rg][c0] = cvt8(a, bq);
    }
  };

  load_chunk(0);
  store_chunk(0);
  __syncthreads();

  for (int ck = 0; ck < NCHUNK; ++ck) {
    const int buf = ck & 1;
    if (ck + 1 < NCHUNK) load_chunk(ck + 1);   // overlap w/ compute below

    // ---- full K: 2 k-halves x {8 nv reads, 16 exps, 5 B reads, 10 MFMAs} ----
    #pragma unroll
    for (int kh = 0; kh < 2; ++kh) {
      float e0[8], e1[8];
      #pragma unroll
      for (int j = 0; j < 8; ++j) {
        // px = 32*kh + 8*lq + j -> permuted row 32*kh + 4*j + lq (conflict-free)
        const float4 nvv = *(const float4*)&nrm4_s[buf][32 * kh + 4 * j + lq][0];
        float t0 = fmaf(qx[0], nvv.x, fmaf(qy[0], nvv.y, fmaf(qz[0], nvv.z, nvv.w)));
        float t1 = fmaf(qx[1], nvv.x, fmaf(qy[1], nvv.y, fmaf(qz[1], nvv.z, nvv.w)));
        e0[j] = __expf(t0);
        e1[j] = __expf(t1);
      }
      short8 a0, a1;
      #pragma unroll
      for (int p = 0; p < 4; ++p) {
        ushort2 p0 = f2b2(e0[2 * p], e0[2 * p + 1]);
        ushort2 p1 = f2b2(e1[2 * p], e1[2 * p + 1]);
        a0[2 * p] = (short)p0.x; a0[2 * p + 1] = (short)p0.y;
        a1[2 * p] = (short)p1.x; a1[2 * p + 1] = (short)p1.y;
      }
      #pragma unroll
      for (int nt = 0; nt < 5; ++nt) {
        short8 bb = *(const short8*)&v_s[buf][16 * nt + mrow][32 * kh + 8 * lq];
        acc[0][nt] = __builtin_amdgcn_mfma_f32_16x16x32_bf16(a0, bb, acc[0][nt], 0, 0, 0);
        acc[1][nt] = __builtin_amdgcn_mfma_f32_16x16x32_bf16(a1, bb, acc[1][nt], 0, 0, 0);
      }
    }

    if (ck + 1 < NCHUNK) {
      store_chunk(buf ^ 1);
      __syncthreads();                 // single barrier per chunk
    }
  }

  // ---- epilogue: no K-merge needed; route extras via small LDS scratch ----
  __syncthreads();                     // all v_s reads done before aliasing
  float* exs = (float*)&v_s[0][0][0];  // [128 q][9] f32 = 4608 B

  const size_t pbase = (size_t)ks * PLANE + ((size_t)b * NQP + (size_t)(qt * QT)) * NCHA_P;
  #pragma unroll
  for (int h = 0; h < 2; ++h) {
    #pragma unroll
    for (int nt = 0; nt < 4; ++nt)
      #pragma unroll
      for (int rr = 0; rr < 4; ++rr) {
        int qloc = 32 * wv + 16 * h + 4 * lq + rr;
        part[pbase + (size_t)qloc * NCHA_P + (size_t)(16 * nt + mrow)] =
            __float2half(acc[h][nt][rr]);
      }
    if (mrow < 7) {
      #pragma unroll
      for (int rr = 0; rr < 4; ++rr)
        exs[(32 * wv + 16 * h + 4 * lq + rr) * 9 + mrow] = acc[h][4][rr];
    }
  }
  __syncthreads();
  if (t < QT) {
    float gx, gy, gz;
    pix2qn(g_qtab.idx[qt * QT + t], gx, gy, gz);
    const float* E = exs + t * 9;
    float swc = gx * E[3] + gy * E[4] + gz * E[5];
    size_t o = pbase + (size_t)t * NCHA_P;
    part[o + 64] = __float2half(E[0]);
    part[o + 65] = __float2half(E[1]);
    part[o + 66] = __float2half(E[2]);
    part[o + 67] = __float2half(swc);
    part[o + 68] = __float2half(E[6]);
    part[o + 69] = __float2half(0.f);   // pad channels: defined zeros
    part[o + 70] = __float2half(0.f);
    part[o + 71] = __float2half(0.f);
  }
}

// finalize: blocks 0..447 reduce+normalize+scatter, 4 queries each.
// Phase 1: 4q x 72ch = 36 aligned 16B units; thread = (unit u<36, k-seg kp<7)
// -> 252/256 threads active, worst thread ceil(ksc/7)=10 uint4 loads (was 64
// half2). LDS tree combines the 7 k-segments. Blocks 448..895 zero-fill.
#define NFIN 448                      // 2 * (NQP/4)
#define NTAIL (2 * NFIN)              // 896 total blocks

__global__ __launch_bounds__(256) void finalize_kernel(
    const __half* __restrict__ part,
    float* __restrict__ out,
    int ksc)
{
  const int blk = blockIdx.x;
  const int t   = threadIdx.x;

  if (blk < NFIN) {
    __shared__ float red[7][36][8];   // 8064 B: per-(kseg, unit) partial sums
    __shared__ float sm[4][NCHA_P];   // 1152 B: combined per-query channels
    const int b   = blk / (NFIN / 2);
    const int rem = blk % (NFIN / 2);
    const int q0  = rem * 4;          // queries q0..q0+3

    // phase 1: 7-way k-split column reduction, uint4 (8-half) loads
    if (t < 252) {
      const int u  = t % 36;          // 16B unit within the 4q x 72ch column
      const int kp = t / 36;          // k segment 0..6
      const int kc = (ksc + 6) / 7;
      const int k0 = kp * kc;
      const int k1 = (k0 + kc < ksc) ? (k0 + kc) : ksc;
      const uint4* pb = (const uint4*)(part + ((size_t)b * NQP + (size_t)q0) * NCHA_P);
      float s0 = 0.f, s1 = 0.f, s2 = 0.f, s3 = 0.f;
      float s4 = 0.f, s5 = 0.f, s6 = 0.f, s7 = 0.f;
      for (int k = k0; k < k1; ++k) {
        uint4 w = pb[(size_t)k * (PLANE / 8) + (size_t)u];
        const __half2* h2 = (const __half2*)&w;
        float2 f;
        f = __half22float2(h2[0]); s0 += f.x; s1 += f.y;
        f = __half22float2(h2[1]); s2 += f.x; s3 += f.y;
        f = __half22float2(h2[2]); s4 += f.x; s5 += f.y;
        f = __half22float2(h2[3]); s6 += f.x; s7 += f.y;
      }
      *(float4*)&red[kp][u][0] = make_float4(s0, s1, s2, s3);
      *(float4*)&red[kp][u][4] = make_float4(s4, s5, s6, s7);
    }
    __syncthreads();

    // phase 1b: combine the 7 k-segments (36 threads)
    if (t < 36) {
      const int q  = t / 9;
      const int c0 = (t % 9) * 8;
      #pragma unroll
      for (int j = 0; j < 8; ++j) {
        float x = 0.f;
        #pragma unroll
        for (int kp = 0; kp < 7; ++kp) x += red[kp][t][j];
        sm[q][c0 + j] = x;
      }
    }
    __syncthreads();

    // phase 2: normalize + scatter (276 outputs over 256 threads)
    for (int i = t; i < 4 * NCHA; i += 256) {
      const int ql = i / NCHA;        // 0..3
      const int oc = i % NCHA;        // output channel
      const int pix = g_qtab.idx[q0 + ql];
      if (pix < 0) continue;
      const float* A = sm[ql];
      const float inv = 1.0f / (A[68] + 1e-9f);
      float gx, gy, gz;
      pix2qn(pix, gx, gy, gz);
      float val;
      if (oc == 0)      val = A[67] * inv;               // rm_cos
      else if (oc == 1) {                                // var
        val = 0.f;
        #pragma unroll
        for (int j = 0; j < 3; ++j) {
          float m  = A[61 + j] * inv;
          float sq = A[64 + j] * inv;
          val += sq - m * m;
        }
      }
      else if (oc == 2) val = gx;
      else if (oc == 3) val = gy;
      else if (oc == 4) val = gz;
      else              val = A[oc - 5] * inv;           // mapped features
      out[((size_t)b * NCHA + (size_t)oc) * 4096 + pix] = val;
    }
  } else {
    // zero-fill: all invalid-pixel slots across both batches (disjoint writes)
    const int start = (blk - NFIN) * 256 + t;
    const int strd  = (NTAIL - NFIN) * 256;
    const int TOT   = 2 * NCHA * 4096;
    for (int i = start; i < TOT; i += strd) {
      if (g_qtab.rank[i & 4095] < 0) out[i] = 0.0f;
    }
  }
}

extern "C" void kernel_launch(void* const* d_in, const int* in_sizes, int n_in,
                              void* d_out, int out_size, void* d_ws, size_t ws_size,
                              hipStream_t stream) {
  const float* fea = (const float*)d_in[0];
  const float* nrm = (const float*)d_in[1];
  const float* msk = (const float*)d_in[2];
  const float* lqn = (const float*)d_in[3];
  __half* part = (__half*)d_ws;
  float* out  = (float*)d_out;

  const size_t need64 = (size_t)64 * PLANE * sizeof(__half);   // 16.5 MB
  const size_t need32 = (size_t)32 * PLANE * sizeof(__half);   // 8.3 MB
  if (ws_size >= need64) {
    partial_kernel<64><<<dim3(2 * 64 * NQT), 256, 0, stream>>>(fea, nrm, msk, lqn, part);
    finalize_kernel<<<dim3(NTAIL), 256, 0, stream>>>(part, out, 64);
  } else if (ws_size >= need32) {
    partial_kernel<32><<<dim3(2 * 32 * NQT), 256, 0, stream>>>(fea, nrm, msk, lqn, part);
    finalize_kernel<<<dim3(NTAIL), 256, 0, stream>>>(part, out, 32);
  } else {
    partial_kernel<16><<<dim3(2 * 16 * NQT), 256, 0, stream>>>(fea, nrm, msk, lqn, part);
    finalize_kernel<<<dim3(NTAIL), 256, 0, stream>>>(part, out, 16);
  }
}